// Round 6
// baseline (186.454 us; speedup 1.0000x reference)
//
#include <hip/hip_runtime.h>
#include <stdint.h>

#define NTOK 8192
#define INF  4096
#define OUTF 4096
#define KDIM 4096

using i32x4 = __attribute__((ext_vector_type(4))) int;

#define GLOAD16(gp, lp) __builtin_amdgcn_global_load_lds( \
    (const __attribute__((address_space(1))) uint32_t*)(gp), \
    (__attribute__((address_space(3))) uint32_t*)(lp), 16, 0, 0)

#define SBAR()  do { __builtin_amdgcn_s_barrier(); __builtin_amdgcn_sched_barrier(0); } while (0)
#define VMCNT4() do { asm volatile("s_waitcnt vmcnt(4)" ::: "memory"); __builtin_amdgcn_sched_barrier(0); } while (0)
#define VMCNT0() do { asm volatile("s_waitcnt vmcnt(0)" ::: "memory"); __builtin_amdgcn_sched_barrier(0); } while (0)

// ---------------- pack pass: fp32 -> int8 sign (+1 / -1) --------------------
__global__ void pack_i8(const float* __restrict__ x, const float* __restrict__ w,
                        char* __restrict__ xp, char* __restrict__ wp,
                        int gx, int gtot) {
    int gtid = blockIdx.x * blockDim.x + threadIdx.x;
    int nthr = gridDim.x * blockDim.x;
    for (int g = gtid; g < gtot; g += nthr) {
        const float* src;
        char* dst;
        int gi;
        if (g < gx) { src = x; dst = xp; gi = g; }
        else        { src = w; dst = wp; gi = g - gx; }
        const float4* s4 = reinterpret_cast<const float4*>(src + (size_t)gi * 16);
        int words[4];
#pragma unroll
        for (int q = 0; q < 4; ++q) {
            float4 v = s4[q];
            int b0 = (v.x < 0.0f) ? 0xFF : 0x01;
            int b1 = (v.y < 0.0f) ? 0xFF : 0x01;
            int b2 = (v.z < 0.0f) ? 0xFF : 0x01;
            int b3 = (v.w < 0.0f) ? 0xFF : 0x01;
            words[q] = b0 | (b1 << 8) | (b2 << 16) | (b3 << 24);
        }
        int4 o = make_int4(words[0], words[1], words[2], words[3]);
        *reinterpret_cast<int4*>(dst + (size_t)gi * 16) = o;
    }
}

// ---------------- i8 MFMA GEMM, 256x256 8-phase schedule + XCD swizzle ------
// Same verified schedule as R5. New: T1 XCD-aware block remap (nwg=512,
// 512%8==0 -> chunked bijection), within-chunk column-major 4x16 walk so each
// XCD keeps its 4 A-panels (4 MB = L2) resident and streams B-panels with
// 4x back-to-back reuse. Compute core unchanged.
__global__ __launch_bounds__(512, 2) void bgemm_i8_8ph(
        const char*  __restrict__ Xp,   // [NTOK][KDIM] i8 (+1/-1)
        const char*  __restrict__ Wp,   // [OUTF][KDIM] i8
        const float* __restrict__ bias, // [OUTF]
        float*       __restrict__ out)  // [NTOK][OUTF]
{
    __shared__ __align__(16) char As[2][32768];
    __shared__ __align__(16) char Bs[2][32768];

    const int tid  = threadIdx.x;
    const int lane = tid & 63;
    const int wid  = tid >> 6;          // 0..7
    const int wr   = wid >> 2;          // 0..1 (M half)
    const int wc   = wid & 3;           // 0..3 (N quarter)
    const int cl   = lane & 15;
    const int rg   = lane >> 4;

    // ---- T1: XCD swizzle. orig&7 = XCD (round-robin dispatch) -> chunk of
    // 64 contiguous logical tiles. Chunk k covers row-tiles [4k,4k+4) x all
    // 16 col-tiles; within-chunk column-major: 4 consecutive share col-tile.
    const int orig = blockIdx.x;                 // 0..511
    const int wgid = ((orig & 7) << 6) | (orig >> 3);
    const int chunk = wgid >> 6;                 // 0..7
    const int c     = wgid & 63;                 // 0..63
    const int tyi   = (chunk << 2) | (c & 3);    // row-tile 0..31
    const int txi   = c >> 2;                    // col-tile 0..15
    const int row0 = tyi * 256;
    const int col0 = txi * 256;

    // staging: thread covers LDS row rr=tid>>3, byte-col (tid&7)*16;
    // source col pre-swizzled: colb ^ ((rr&7)<<4)  (rule 21: both-sides)
    const int rr     = tid >> 3;                       // 0..63
    const int colOff = ((tid & 7) << 4) ^ ((rr & 7) << 4);
    const char* gA = Xp + (size_t)(row0 + rr) * KDIM + colOff;
    const char* gB = Wp + (size_t)(col0 + rr) * KDIM + colOff;
    const int d0 = tid * 16;

#define STG(arr, p, g, h, ktB) do { \
    GLOAD16((g) + (size_t)((h) * 128) * KDIM + (ktB),      &arr[p][(h) * 16384 + d0]); \
    GLOAD16((g) + (size_t)((h) * 128 + 64) * KDIM + (ktB), &arr[p][(h) * 16384 + 8192 + d0]); \
} while (0)

    // fragment read addressing (K-invariant, swizzled)
    const int aRow = (wr * 128 + cl) * 128;
    const int bRow = (wc * 64 + cl) * 128;
    const int kq0  = (rg << 4) ^ ((cl & 7) << 4);
    const int kq1  = kq0 ^ 64;

    i32x4 acc[8][4];
#pragma unroll
    for (int m = 0; m < 8; ++m)
#pragma unroll
        for (int n = 0; n < 4; ++n)
#pragma unroll
            for (int j = 0; j < 4; ++j) acc[m][n][j] = 0;

    i32x4 af[4][2], bf0[2][2], bf1[2][2];

#define LDA(p, MH) do { \
    _Pragma("unroll") for (int m = 0; m < 4; ++m) { \
        af[m][0] = *reinterpret_cast<const i32x4*>(&As[p][aRow + ((MH) * 4 + m) * 2048 + kq0]); \
        af[m][1] = *reinterpret_cast<const i32x4*>(&As[p][aRow + ((MH) * 4 + m) * 2048 + kq1]); \
    } } while (0)
#define LDB(p, NH, bf) do { \
    _Pragma("unroll") for (int n = 0; n < 2; ++n) { \
        bf[n][0] = *reinterpret_cast<const i32x4*>(&Bs[p][bRow + ((NH) * 2 + n) * 2048 + kq0]); \
        bf[n][1] = *reinterpret_cast<const i32x4*>(&Bs[p][bRow + ((NH) * 2 + n) * 2048 + kq1]); \
    } } while (0)
#define MM(MH, NH, bf) do { \
    __builtin_amdgcn_s_setprio(1); \
    _Pragma("unroll") for (int m = 0; m < 4; ++m) \
    _Pragma("unroll") for (int n = 0; n < 2; ++n) \
    _Pragma("unroll") for (int kk = 0; kk < 2; ++kk) \
        acc[(MH) * 4 + m][(NH) * 2 + n] = __builtin_amdgcn_mfma_i32_16x16x64_i8( \
            af[m][kk], bf[n][kk], acc[(MH) * 4 + m][(NH) * 2 + n], 0, 0, 0); \
    __builtin_amdgcn_s_setprio(0); \
} while (0)

    // ---- prologue: tile0 (8 loads) + tile1 h0 (4 loads); retire tile0 -----
    STG(As, 0, gA, 0, 0);   STG(As, 0, gA, 1, 0);
    STG(Bs, 0, gB, 0, 0);   STG(Bs, 0, gB, 1, 0);
    STG(Bs, 1, gB, 0, 128); STG(As, 1, gA, 0, 128);
    VMCNT4();
    SBAR();

    // ---- main loop: tile 2it (p0) in ph0-3, tile 2it+1 (p1) in ph4-7 ------
    int kb = 0;  // = it*256
#pragma unroll 1
    for (int it = 0; it < 15; ++it, kb += 256) {
        // ph0: read A(p0,MH0)+B(p0,NH0) ; stage B.p1.h1 (tile 2it+1)
        LDA(0, 0); LDB(0, 0, bf0);
        STG(Bs, 1, gB, 1, kb + 128);
        SBAR(); MM(0, 0, bf0); SBAR();
        // ph1: read B(p0,NH1) ; stage A.p1.h1 (tile 2it+1)
        LDB(0, 1, bf1);
        STG(As, 1, gA, 1, kb + 128);
        SBAR(); MM(0, 1, bf1); SBAR();
        // ph2: read A(p0,MH1) ; stage B.p0.h0 (tile 2it+2)
        LDA(0, 1);
        STG(Bs, 0, gB, 0, kb + 256);
        SBAR(); MM(1, 1, bf1); SBAR();
        // ph3: stage A.p0.h0 (tile 2it+2) ; vmcnt(4) retires tile 2it+1
        STG(As, 0, gA, 0, kb + 256);
        SBAR(); MM(1, 0, bf0);
        VMCNT4(); SBAR();
        // ph4: read A(p1,MH0)+B(p1,NH0) ; stage B.p0.h1 (tile 2it+2)
        LDA(1, 0); LDB(1, 0, bf0);
        STG(Bs, 0, gB, 1, kb + 256);
        SBAR(); MM(0, 0, bf0); SBAR();
        // ph5: read B(p1,NH1) ; stage A.p0.h1 (tile 2it+2)
        LDB(1, 1, bf1);
        STG(As, 0, gA, 1, kb + 256);
        SBAR(); MM(0, 1, bf1); SBAR();
        // ph6: read A(p1,MH1) ; stage B.p1.h0 (tile 2it+3)
        LDA(1, 1);
        STG(Bs, 1, gB, 0, kb + 384);
        SBAR(); MM(1, 1, bf1); SBAR();
        // ph7: stage A.p1.h0 (tile 2it+3) ; vmcnt(4) retires tile 2it+2
        STG(As, 1, gA, 0, kb + 384);
        SBAR(); MM(1, 0, bf0);
        VMCNT4(); SBAR();
    }

    // ---- epilogue: tile31 h1, drain, compute tiles 30 and 31 --------------
    STG(Bs, 1, gB, 1, 3968);
    STG(As, 1, gA, 1, 3968);
    VMCNT0();
    SBAR();
    // tile 30 (p0)
    LDA(0, 0); LDB(0, 0, bf0); MM(0, 0, bf0);
    LDB(0, 1, bf1);            MM(0, 1, bf1);
    LDA(0, 1);                 MM(1, 1, bf1);
                               MM(1, 0, bf0);
    // tile 31 (p1)
    LDA(1, 0); LDB(1, 0, bf0); MM(0, 0, bf0);
    LDB(1, 1, bf1);            MM(0, 1, bf1);
    LDA(1, 1);                 MM(1, 1, bf1);
                               MM(1, 0, bf0);

    // ---- C write: C/D layout col=lane&15, row=rg*4+j ----------------------
    float bv[4];
#pragma unroll
    for (int n = 0; n < 4; ++n) bv[n] = bias[col0 + wc * 64 + n * 16 + cl];

#pragma unroll
    for (int m = 0; m < 8; ++m) {
        int rowbase = row0 + wr * 128 + m * 16 + rg * 4;
#pragma unroll
        for (int j = 0; j < 4; ++j) {
            size_t rb = (size_t)(rowbase + j) * OUTF;
#pragma unroll
            for (int n = 0; n < 4; ++n) {
                int col = col0 + wc * 64 + n * 16 + cl;
                out[rb + col] = (float)acc[m][n][j] + bv[n];
            }
        }
    }
#undef STG
#undef LDA
#undef LDB
#undef MM
}

// ================= fallback (round-1 popcount path, known-good) =============
#define KW   64
#define LSTRIDE 66

__global__ void pack_both_fb(const float* __restrict__ x, const float* __restrict__ w,
                             uint64_t* __restrict__ xp, uint64_t* __restrict__ wp,
                             int nx, int ntot) {
    int gtid  = blockIdx.x * blockDim.x + threadIdx.x;
    int lane  = threadIdx.x & 63;
    int wave  = gtid >> 6;
    int nwaves = (gridDim.x * blockDim.x) >> 6;
    for (int q = wave; q < ntot; q += nwaves) {
        const float* src; uint64_t* dst; int qi;
        if (q < nx) { src = x; dst = xp; qi = q; }
        else        { src = w; dst = wp; qi = q - nx; }
        float v = src[(size_t)qi * 64 + lane];
        unsigned long long m = __ballot(v < 0.0f);
        if (lane == 0) dst[qi] = (uint64_t)m;
    }
}

__global__ __launch_bounds__(512, 2) void bgemm_popc_fb(
        const uint64_t* __restrict__ xp, const uint64_t* __restrict__ wp,
        const float* __restrict__ bias, float* __restrict__ out)
{
    __shared__ uint64_t xs[128 * LSTRIDE];
    __shared__ uint64_t ws[128 * LSTRIDE];
    const int tid  = threadIdx.x;
    const int row0 = blockIdx.y * 128;
    const int col0 = blockIdx.x * 128;
    {
        const uint64_t* xg = xp + (size_t)row0 * KW;
        const uint64_t* wg = wp + (size_t)col0 * KW;
#pragma unroll
        for (int m = 0; m < 8; ++m) {
            int q = (m * 512 + tid) * 2;
            int r = q >> 6;
            int k = q & 63;
            ulonglong2 vx = *reinterpret_cast<const ulonglong2*>(xg + q);
            xs[r * LSTRIDE + k] = vx.x; xs[r * LSTRIDE + k + 1] = vx.y;
            ulonglong2 vw = *reinterpret_cast<const ulonglong2*>(wg + q);
            ws[r * LSTRIDE + k] = vw.x; ws[r * LSTRIDE + k + 1] = vw.y;
        }
    }
    __syncthreads();
    const int tx = tid & 15;
    const int ty = tid >> 4;
    int acc[4][8];
#pragma unroll
    for (int i = 0; i < 4; ++i)
#pragma unroll
        for (int j = 0; j < 8; ++j) acc[i][j] = 0;
    const uint64_t* xrow = xs + ty * 4 * LSTRIDE;
    const uint64_t* wrow = ws + tx * LSTRIDE;
#pragma unroll 4
    for (int kk = 0; kk < KW; kk += 2) {
        ulonglong2 a[4]; ulonglong2 b[8];
#pragma unroll
        for (int i = 0; i < 4; ++i)
            a[i] = *reinterpret_cast<const ulonglong2*>(xrow + i * LSTRIDE + kk);
#pragma unroll
        for (int j = 0; j < 8; ++j)
            b[j] = *reinterpret_cast<const ulonglong2*>(wrow + j * 16 * LSTRIDE + kk);
#pragma unroll
        for (int i = 0; i < 4; ++i)
#pragma unroll
            for (int j = 0; j < 8; ++j)
                acc[i][j] += __builtin_popcountll(a[i].x ^ b[j].x)
                           + __builtin_popcountll(a[i].y ^ b[j].y);
    }
    float bcol[8];
#pragma unroll
    for (int j = 0; j < 8; ++j) bcol[j] = bias[col0 + tx + 16 * j];
#pragma unroll
    for (int i = 0; i < 4; ++i) {
        size_t r = (size_t)(row0 + ty * 4 + i);
#pragma unroll
        for (int j = 0; j < 8; ++j) {
            int c = col0 + tx + 16 * j;
            out[r * OUTF + c] = (float)(INF - 2 * acc[i][j]) + bcol[j];
        }
    }
}
// ============================================================================

extern "C" void kernel_launch(void* const* d_in, const int* in_sizes, int n_in,
                              void* d_out, int out_size, void* d_ws, size_t ws_size,
                              hipStream_t stream) {
    const float* x    = (const float*)d_in[0];
    const float* w    = (const float*)d_in[1];
    const float* bias = (const float*)d_in[2];
    float* out = (float*)d_out;

    const size_t need = (size_t)NTOK * KDIM + (size_t)OUTF * KDIM; // 50.3 MB
    if (ws_size >= need) {
        char* xp = (char*)d_ws;
        char* wp = xp + (size_t)NTOK * KDIM;
        const int gx   = NTOK * KDIM / 16;
        const int gtot = gx + OUTF * KDIM / 16;
        pack_i8<<<2048, 256, 0, stream>>>(x, w, xp, wp, gx, gtot);
        bgemm_i8_8ph<<<512, 512, 0, stream>>>(xp, wp, bias, out);  // 1-D grid, swizzled inside
    } else {
        uint64_t* xp = (uint64_t*)d_ws;
        uint64_t* wp = xp + (size_t)NTOK * KW;
        const int nx   = NTOK * KW;
        const int ntot = nx + OUTF * KW;
        pack_both_fb<<<2048, 256, 0, stream>>>(x, w, xp, wp, nx, ntot);
        dim3 grid(OUTF / 128, NTOK / 128);
        bgemm_popc_fb<<<grid, 512, 0, stream>>>(xp, wp, bias, out);
    }
}

// Round 7
// 178.185 us; speedup vs baseline: 1.0464x; 1.0464x over previous
//
#include <hip/hip_runtime.h>
#include <stdint.h>

#define NTOK 8192
#define INF  4096
#define OUTF 4096
#define KDIM 4096

using i32x4 = __attribute__((ext_vector_type(4))) int;

#define GLOAD16(gp, lp) __builtin_amdgcn_global_load_lds( \
    (const __attribute__((address_space(1))) uint32_t*)(gp), \
    (__attribute__((address_space(3))) uint32_t*)(lp), 16, 0, 0)

#define SBARP()  do { __builtin_amdgcn_s_barrier(); __builtin_amdgcn_sched_barrier(0); } while (0)
#define SBARX()  __builtin_amdgcn_s_barrier()
#define VMCNT4() do { asm volatile("s_waitcnt vmcnt(4)" ::: "memory"); __builtin_amdgcn_sched_barrier(0); } while (0)
#define VMCNT0() do { asm volatile("s_waitcnt vmcnt(0)" ::: "memory"); __builtin_amdgcn_sched_barrier(0); } while (0)

// ---------------- pack pass: fp32 -> int8 sign (+1 / -1) --------------------
__global__ void pack_i8(const float* __restrict__ x, const float* __restrict__ w,
                        char* __restrict__ xp, char* __restrict__ wp,
                        int gx, int gtot) {
    int gtid = blockIdx.x * blockDim.x + threadIdx.x;
    int nthr = gridDim.x * blockDim.x;
    for (int g = gtid; g < gtot; g += nthr) {
        const float* src;
        char* dst;
        int gi;
        if (g < gx) { src = x; dst = xp; gi = g; }
        else        { src = w; dst = wp; gi = g - gx; }
        const float4* s4 = reinterpret_cast<const float4*>(src + (size_t)gi * 16);
        int words[4];
#pragma unroll
        for (int q = 0; q < 4; ++q) {
            float4 v = s4[q];
            int b0 = (v.x < 0.0f) ? 0xFF : 0x01;
            int b1 = (v.y < 0.0f) ? 0xFF : 0x01;
            int b2 = (v.z < 0.0f) ? 0xFF : 0x01;
            int b3 = (v.w < 0.0f) ? 0xFF : 0x01;
            words[q] = b0 | (b1 << 8) | (b2 << 16) | (b3 << 24);
        }
        int4 o = make_int4(words[0], words[1], words[2], words[3]);
        *reinterpret_cast<int4*>(dst + (size_t)gi * 16) = o;
    }
}

// ---------------- i8 MFMA GEMM, 256x256, 4-phase schedule -------------------
// 512 thr = 8 waves (2M x 4N); per-wave 128x64 out = 8x4 frags. K-tile 128 B.
// 4 phases per iteration (2 K-tiles); 32-MFMA clusters (one M-half x all N x
// K-tile). Half the barriers/lgkm-drains of the 8-phase version; same bytes.
// Ledger (gload units, FIFO, carry-in 4 = B.p1(t+1)):
//   ph0: read A.p0(MH0)+B.p0(all); stage A.p1<-t+1        (outst 8)
//   ph1: read A.p0(MH1);           stage B.p0<-t+2; vmcnt(4)  (12->4)
//   ph2: read A.p1(MH0)+B.p1(all); stage A.p0<-t+2        (outst 8)
//   ph3: read A.p1(MH1);           stage B.p1<-t+3; vmcnt(4)  (12->4)
// Every stage issues after the barrier closing its slot's last read.
__global__ __launch_bounds__(512, 2) void bgemm_i8_4ph(
        const char*  __restrict__ Xp,   // [NTOK][KDIM] i8 (+1/-1)
        const char*  __restrict__ Wp,   // [OUTF][KDIM] i8
        const float* __restrict__ bias, // [OUTF]
        float*       __restrict__ out)  // [NTOK][OUTF]
{
    __shared__ __align__(16) char As[2][32768];
    __shared__ __align__(16) char Bs[2][32768];

    const int tid  = threadIdx.x;
    const int lane = tid & 63;
    const int wid  = tid >> 6;          // 0..7
    const int wr   = wid >> 2;          // 0..1 (M half)
    const int wc   = wid & 3;           // 0..3 (N quarter)
    const int cl   = lane & 15;
    const int rg   = lane >> 4;

    // T1 XCD swizzle (kept: halves FETCH, free). 512 blocks, 8 XCDs.
    const int orig = blockIdx.x;                 // 0..511
    const int wgid = ((orig & 7) << 6) | (orig >> 3);
    const int chunk = wgid >> 6;                 // 0..7
    const int c     = wgid & 63;                 // 0..63
    const int tyi   = (chunk << 2) | (c & 3);    // row-tile 0..31
    const int txi   = c >> 2;                    // col-tile 0..15
    const int row0 = tyi * 256;
    const int col0 = txi * 256;

    // staging: thread covers LDS row rr=tid>>3, byte-col (tid&7)*16;
    // source col pre-swizzled: colb ^ ((rr&7)<<4)  (rule 21: both-sides)
    const int rr     = tid >> 3;                       // 0..63
    const int colOff = ((tid & 7) << 4) ^ ((rr & 7) << 4);
    const char* gA = Xp + (size_t)(row0 + rr) * KDIM + colOff;
    const char* gB = Wp + (size_t)(col0 + rr) * KDIM + colOff;
    const int d0 = tid * 16;

    // STGF: stage one FULL 256-row tile (4 gload_lds_dwordx4 per thread)
#define STGF(arr, p, g, ktB) do { \
    GLOAD16((g) + (size_t)0   * KDIM + (ktB), &arr[p][d0]); \
    GLOAD16((g) + (size_t)64  * KDIM + (ktB), &arr[p][8192 + d0]); \
    GLOAD16((g) + (size_t)128 * KDIM + (ktB), &arr[p][16384 + d0]); \
    GLOAD16((g) + (size_t)192 * KDIM + (ktB), &arr[p][24576 + d0]); \
} while (0)

    // fragment read addressing (K-invariant, swizzled)
    const int aRow = (wr * 128 + cl) * 128;
    const int bRow = (wc * 64 + cl) * 128;
    const int kq0  = (rg << 4) ^ ((cl & 7) << 4);
    const int kq1  = kq0 ^ 64;

    i32x4 acc[8][4];
#pragma unroll
    for (int m = 0; m < 8; ++m)
#pragma unroll
        for (int n = 0; n < 4; ++n)
#pragma unroll
            for (int j = 0; j < 4; ++j) acc[m][n][j] = 0;

    i32x4 af[4][2], bf[4][2];

#define LDA(p, MH) do { \
    _Pragma("unroll") for (int m = 0; m < 4; ++m) { \
        af[m][0] = *reinterpret_cast<const i32x4*>(&As[p][aRow + ((MH) * 4 + m) * 2048 + kq0]); \
        af[m][1] = *reinterpret_cast<const i32x4*>(&As[p][aRow + ((MH) * 4 + m) * 2048 + kq1]); \
    } } while (0)
#define LDBALL(p) do { \
    _Pragma("unroll") for (int n = 0; n < 4; ++n) { \
        bf[n][0] = *reinterpret_cast<const i32x4*>(&Bs[p][bRow + (n) * 2048 + kq0]); \
        bf[n][1] = *reinterpret_cast<const i32x4*>(&Bs[p][bRow + (n) * 2048 + kq1]); \
    } } while (0)
#define MMALL(MH) do { \
    __builtin_amdgcn_s_setprio(1); \
    _Pragma("unroll") for (int m = 0; m < 4; ++m) \
    _Pragma("unroll") for (int n = 0; n < 4; ++n) \
    _Pragma("unroll") for (int kk = 0; kk < 2; ++kk) \
        acc[(MH) * 4 + m][n] = __builtin_amdgcn_mfma_i32_16x16x64_i8( \
            af[m][kk], bf[n][kk], acc[(MH) * 4 + m][n], 0, 0, 0); \
    __builtin_amdgcn_s_setprio(0); \
} while (0)

    // ---- prologue: A.p0(0), B.p0(0), B.p1(1) = 12 gloads; retire first 8 --
    STGF(As, 0, gA, 0);
    STGF(Bs, 0, gB, 0);
    STGF(Bs, 1, gB, 128);
    VMCNT4();
    SBARX();

    // ---- main loop: tile 2i on p0 (ph0,ph1), tile 2i+1 on p1 (ph2,ph3) ----
    int kb = 0;  // = i*256
#pragma unroll 1
    for (int i = 0; i < 15; ++i, kb += 256) {
        // ph0: read A.p0(MH0)+B.p0(all); stage A.p1 <- tile 2i+1
        LDA(0, 0); LDBALL(0);
        STGF(As, 1, gA, kb + 128);
        SBARP(); MMALL(0); SBARX();
        // ph1: read A.p0(MH1); stage B.p0 <- tile 2i+2 ; vmcnt(4)
        LDA(0, 1);
        STGF(Bs, 0, gB, kb + 256);
        SBARP(); MMALL(1);
        VMCNT4(); SBARX();
        // ph2: read A.p1(MH0)+B.p1(all); stage A.p0 <- tile 2i+2
        LDA(1, 0); LDBALL(1);
        STGF(As, 0, gA, kb + 256);
        SBARP(); MMALL(0); SBARX();
        // ph3: read A.p1(MH1); stage B.p1 <- tile 2i+3 ; vmcnt(4)
        LDA(1, 1);
        STGF(Bs, 1, gB, kb + 384);
        SBARP(); MMALL(1);
        VMCNT4(); SBARX();
    }

    // ---- epilogue: stage A.p1(31); drain; compute tiles 30, 31 ------------
    STGF(As, 1, gA, 3968);
    VMCNT0();
    SBARX();
    // tile 30 (p0)
    LDA(0, 0); LDBALL(0); MMALL(0);
    LDA(0, 1);            MMALL(1);
    // tile 31 (p1)
    LDA(1, 0); LDBALL(1); MMALL(0);
    LDA(1, 1);            MMALL(1);

    // ---- C write: C/D layout col=lane&15, row=rg*4+j ----------------------
    float bv[4];
#pragma unroll
    for (int n = 0; n < 4; ++n) bv[n] = bias[col0 + wc * 64 + n * 16 + cl];

#pragma unroll
    for (int m = 0; m < 8; ++m) {
        int rowbase = row0 + wr * 128 + m * 16 + rg * 4;
#pragma unroll
        for (int j = 0; j < 4; ++j) {
            size_t rb = (size_t)(rowbase + j) * OUTF;
#pragma unroll
            for (int n = 0; n < 4; ++n) {
                int col = col0 + wc * 64 + n * 16 + cl;
                out[rb + col] = (float)acc[m][n][j] + bv[n];
            }
        }
    }
#undef STGF
#undef LDA
#undef LDBALL
#undef MMALL
}

// ================= fallback (round-1 popcount path, known-good) =============
#define KW   64
#define LSTRIDE 66

__global__ void pack_both_fb(const float* __restrict__ x, const float* __restrict__ w,
                             uint64_t* __restrict__ xp, uint64_t* __restrict__ wp,
                             int nx, int ntot) {
    int gtid  = blockIdx.x * blockDim.x + threadIdx.x;
    int lane  = threadIdx.x & 63;
    int wave  = gtid >> 6;
    int nwaves = (gridDim.x * blockDim.x) >> 6;
    for (int q = wave; q < ntot; q += nwaves) {
        const float* src; uint64_t* dst; int qi;
        if (q < nx) { src = x; dst = xp; qi = q; }
        else        { src = w; dst = wp; qi = q - nx; }
        float v = src[(size_t)qi * 64 + lane];
        unsigned long long m = __ballot(v < 0.0f);
        if (lane == 0) dst[qi] = (uint64_t)m;
    }
}

__global__ __launch_bounds__(512, 2) void bgemm_popc_fb(
        const uint64_t* __restrict__ xp, const uint64_t* __restrict__ wp,
        const float* __restrict__ bias, float* __restrict__ out)
{
    __shared__ uint64_t xs[128 * LSTRIDE];
    __shared__ uint64_t ws[128 * LSTRIDE];
    const int tid  = threadIdx.x;
    const int row0 = blockIdx.y * 128;
    const int col0 = blockIdx.x * 128;
    {
        const uint64_t* xg = xp + (size_t)row0 * KW;
        const uint64_t* wg = wp + (size_t)col0 * KW;
#pragma unroll
        for (int m = 0; m < 8; ++m) {
            int q = (m * 512 + tid) * 2;
            int r = q >> 6;
            int k = q & 63;
            ulonglong2 vx = *reinterpret_cast<const ulonglong2*>(xg + q);
            xs[r * LSTRIDE + k] = vx.x; xs[r * LSTRIDE + k + 1] = vx.y;
            ulonglong2 vw = *reinterpret_cast<const ulonglong2*>(wg + q);
            ws[r * LSTRIDE + k] = vw.x; ws[r * LSTRIDE + k + 1] = vw.y;
        }
    }
    __syncthreads();
    const int tx = tid & 15;
    const int ty = tid >> 4;
    int acc[4][8];
#pragma unroll
    for (int i = 0; i < 4; ++i)
#pragma unroll
        for (int j = 0; j < 8; ++j) acc[i][j] = 0;
    const uint64_t* xrow = xs + ty * 4 * LSTRIDE;
    const uint64_t* wrow = ws + tx * LSTRIDE;
#pragma unroll 4
    for (int kk = 0; kk < KW; kk += 2) {
        ulonglong2 a[4]; ulonglong2 b[8];
#pragma unroll
        for (int i = 0; i < 4; ++i)
            a[i] = *reinterpret_cast<const ulonglong2*>(xrow + i * LSTRIDE + kk);
#pragma unroll
        for (int j = 0; j < 8; ++j)
            b[j] = *reinterpret_cast<const ulonglong2*>(wrow + j * 16 * LSTRIDE + kk);
#pragma unroll
        for (int i = 0; i < 4; ++i)
#pragma unroll
            for (int j = 0; j < 8; ++j)
                acc[i][j] += __builtin_popcountll(a[i].x ^ b[j].x)
                           + __builtin_popcountll(a[i].y ^ b[j].y);
    }
    float bcol[8];
#pragma unroll
    for (int j = 0; j < 8; ++j) bcol[j] = bias[col0 + tx + 16 * j];
#pragma unroll
    for (int i = 0; i < 4; ++i) {
        size_t r = (size_t)(row0 + ty * 4 + i);
#pragma unroll
        for (int j = 0; j < 8; ++j) {
            int c = col0 + tx + 16 * j;
            out[r * OUTF + c] = (float)(INF - 2 * acc[i][j]) + bcol[j];
        }
    }
}
// ============================================================================

extern "C" void kernel_launch(void* const* d_in, const int* in_sizes, int n_in,
                              void* d_out, int out_size, void* d_ws, size_t ws_size,
                              hipStream_t stream) {
    const float* x    = (const float*)d_in[0];
    const float* w    = (const float*)d_in[1];
    const float* bias = (const float*)d_in[2];
    float* out = (float*)d_out;

    const size_t need = (size_t)NTOK * KDIM + (size_t)OUTF * KDIM; // 50.3 MB
    if (ws_size >= need) {
        char* xp = (char*)d_ws;
        char* wp = xp + (size_t)NTOK * KDIM;
        const int gx   = NTOK * KDIM / 16;
        const int gtot = gx + OUTF * KDIM / 16;
        pack_i8<<<2048, 256, 0, stream>>>(x, w, xp, wp, gx, gtot);
        bgemm_i8_4ph<<<512, 512, 0, stream>>>(xp, wp, bias, out);  // 1-D grid, swizzled inside
    } else {
        uint64_t* xp = (uint64_t*)d_ws;
        uint64_t* wp = xp + (size_t)NTOK * KW;
        const int nx   = NTOK * KW;
        const int ntot = nx + OUTF * KW;
        pack_both_fb<<<2048, 256, 0, stream>>>(x, w, xp, wp, nx, ntot);
        dim3 grid(OUTF / 128, NTOK / 128);
        bgemm_popc_fb<<<grid, 512, 0, stream>>>(xp, wp, bias, out);
    }
}